// Round 9
// baseline (5187.524 us; speedup 1.0000x reference)
//
#include <hip/hip_runtime.h>

#define TMAX 8192
#define H 128

typedef float v2f __attribute__((ext_vector_type(2)));

// rcp-based activations (v_rcp_f32, ~1 ulp) — proven win in round 7.
__device__ __forceinline__ float sigf(float x) {
    return __builtin_amdgcn_rcpf(1.f + __expf(-x));
}
__device__ __forceinline__ float tanhf_fast(float x) {
    return fmaf(2.f, __builtin_amdgcn_rcpf(1.f + __expf(-2.f * x)), -1.f);
}

// Quad butterfly sum via DPP quad_perm (VALU pipe) — proven in rounds 7/8.
__device__ __forceinline__ float qsum4(float v) {
    int s = __builtin_amdgcn_update_dpp(0, __float_as_int(v), 0xB1, 0xF, 0xF, true); // xor1
    v += __int_as_float(s);
    s = __builtin_amdgcn_update_dpp(0, __float_as_int(v), 0x4E, 0xF, 0xF, true);     // xor2
    v += __int_as_float(s);
    return v;
}

// Guaranteed packed dual-FMA. No tied constraints (separate dst temp -> RA
// coalesces); VOP3P reads all srcs before writing dst, so dst may alias srcs.
#define PKFMA(acc, w, h) { v2f _d; \
    asm("v_pk_fma_f32 %0, %1, %2, %3" : "=v"(_d) : "v"(w), "v"(h), "v"(acc)); \
    acc = _d; }

// One block, 512 threads = 8 waves (2/SIMD).
// Thread t: h-element j = t>>2, k-quarter q = t&3; all 4 gate rows x 32-wide slice.
//
// ROUND 9: VALUBusy arithmetic (249 inst/wave/step vs ~112 ideal) matches a
// per-use AGPR-read tax on parked weights (and/or scalarized elementwise_fma).
// Fix: inner loop as explicit inline-asm v_pk_fma_f32 with "v"-constrained
// weight pairs (guarantees pk encoding + per-use arch-VGPR pressure), h kept
// in LDS as interleaved v2f so ds_read_b64 lands operands in pk form with
// zero repack movs. Loop unrolled x2 for static double-buffer addressing.
__attribute__((amdgpu_waves_per_eu(2, 2)))
__global__ __launch_bounds__(512)
void lstm_seq_kernel(const float* __restrict__ x,
                     const float* __restrict__ Wih,
                     const float* __restrict__ Whh,
                     const float* __restrict__ bih,
                     const float* __restrict__ bhh,
                     const float* __restrict__ Wlin,
                     const float* __restrict__ blin,
                     const float* __restrict__ h0,
                     const float* __restrict__ c0,
                     float* __restrict__ out,
                     int T)
{
    __shared__ float x_s[TMAX];   // 32 KB
    // Interleaved v2f h buffers: slot s = p*4 + q holds h[q*32 + 2p .. +1],
    // p = 0..15. 4 q-groups of a wave read 4 distinct slots (broadcast across
    // the 16 j-lanes), landing on disjoint banks -> conflict-free b64 reads.
    __shared__ v2f hA[64], hB[64];

    const int t = threadIdx.x;    // 0..511
    const int j = t >> 2;         // h element 0..127
    const int q = t & 3;          // k-quarter

    for (int idx = t; idx < T; idx += 512) x_s[idx] = x[idx];

    const float4* pi = (const float4*)(Whh + (j      ) * H + q * 32);
    const float4* pf = (const float4*)(Whh + (j + 128) * H + q * 32);
    const float4* pg = (const float4*)(Whh + (j + 256) * H + q * 32);
    const float4* po = (const float4*)(Whh + (j + 384) * H + q * 32);

    // One-shot weight loads (asm volatile: issued exactly once, not remat-able).
#define ASMLD4(dst, base, n) \
    { const float4* _a = (base) + (n); \
      asm volatile("global_load_dwordx4 %0, %1, off" : "=v"(dst) : "v"(_a)); }
    float4 wi0, wi1, wi2, wi3, wi4, wi5, wi6, wi7;
    float4 wf0, wf1, wf2, wf3, wf4, wf5, wf6, wf7;
    float4 wg0, wg1, wg2, wg3, wg4, wg5, wg6, wg7;
    float4 wo0, wo1, wo2, wo3, wo4, wo5, wo6, wo7;
#define LOADW(n) \
    ASMLD4(wi##n, pi, n) ASMLD4(wf##n, pf, n) ASMLD4(wg##n, pg, n) ASMLD4(wo##n, po, n)
    LOADW(0) LOADW(1) LOADW(2) LOADW(3) LOADW(4) LOADW(5) LOADW(6) LOADW(7)
#undef LOADW
#undef ASMLD4

#define ASMLD1(dst, ptr) \
    { const float* _a = (ptr); \
      asm volatile("global_load_dword %0, %1, off" : "=v"(dst) : "v"(_a)); }
    float wxi, wxf, wxg, wxo, vbi, vbf, vbg, vbo, vb2i, vb2f, vb2g, vb2o;
    ASMLD1(wxi, Wih + j)        ASMLD1(wxf, Wih + j + 128)
    ASMLD1(wxg, Wih + j + 256)  ASMLD1(wxo, Wih + j + 384)
    ASMLD1(vbi, bih + j)        ASMLD1(vbf, bih + j + 128)
    ASMLD1(vbg, bih + j + 256)  ASMLD1(vbo, bih + j + 384)
    ASMLD1(vb2i, bhh + j)       ASMLD1(vb2f, bhh + j + 128)
    ASMLD1(vb2g, bhh + j + 256) ASMLD1(vb2o, bhh + j + 384)
#undef ASMLD1

    asm volatile("s_waitcnt vmcnt(0)");
    __builtin_amdgcn_sched_barrier(0);   // rule #18: nothing hoists above the wait

    // Split each weight float4 into two v2f halves: {x,y} covers h-pair p=2n,
    // {z,w} covers p=2n+1.
#define SPLIT(G,n) \
    v2f G##a##n = {w##G##n.x, w##G##n.y}; \
    v2f G##b##n = {w##G##n.z, w##G##n.w};
    SPLIT(i,0) SPLIT(i,1) SPLIT(i,2) SPLIT(i,3) SPLIT(i,4) SPLIT(i,5) SPLIT(i,6) SPLIT(i,7)
    SPLIT(f,0) SPLIT(f,1) SPLIT(f,2) SPLIT(f,3) SPLIT(f,4) SPLIT(f,5) SPLIT(f,6) SPLIT(f,7)
    SPLIT(g,0) SPLIT(g,1) SPLIT(g,2) SPLIT(g,3) SPLIT(g,4) SPLIT(g,5) SPLIT(g,6) SPLIT(g,7)
    SPLIT(o,0) SPLIT(o,1) SPLIT(o,2) SPLIT(o,3) SPLIT(o,4) SPLIT(o,5) SPLIT(o,6) SPLIT(o,7)
#undef SPLIT

    const bool lead = (q == 0);
    if (!lead) { wxi = 0.f; wxf = 0.f; wxg = 0.f; wxo = 0.f; }
    const float bi_ = lead ? vbi + vb2i : 0.f;
    const float bf_ = lead ? vbf + vb2f : 0.f;
    const float bg_ = lead ? vbg + vb2g : 0.f;
    const float bo_ = lead ? vbo + vb2o : 0.f;

    float c = c0[j];              // replicated across the 4 lanes of a group

    // element e -> float index in the interleaved v2f array:
    //   qe = e>>5, pe = (e&31)>>1, half = e&1  ->  8*pe + 2*qe + half
    if (t < H) {
        const int fi = 8 * ((t & 31) >> 1) + 2 * (t >> 5) + (t & 1);
        ((float*)hA)[fi] = h0[t];
    }
    const int widx = 8 * ((j & 31) >> 1) + 2 * (j >> 5) + (j & 1);
    __syncthreads();

#define DO(n, hrd) { \
        const v2f h2a = hrd[8 * n + q]; \
        const v2f h2b = hrd[8 * n + 4 + q]; \
        PKFMA(aci, i##a##n, h2a) PKFMA(aci, i##b##n, h2b) \
        PKFMA(acf, f##a##n, h2a) PKFMA(acf, f##b##n, h2b) \
        PKFMA(acg, g##a##n, h2a) PKFMA(acg, g##b##n, h2b) \
        PKFMA(aco, o##a##n, h2a) PKFMA(aco, o##b##n, h2b) }

#define STEP(hrd, hwr, sidx) { \
        const float xv = x_s[sidx]; \
        v2f aci = {fmaf(xv, wxi, bi_), 0.f}; \
        v2f acf = {fmaf(xv, wxf, bf_), 0.f}; \
        v2f acg = {fmaf(xv, wxg, bg_), 0.f}; \
        v2f aco = {fmaf(xv, wxo, bo_), 0.f}; \
        DO(0, hrd) DO(1, hrd) DO(2, hrd) DO(3, hrd) \
        DO(4, hrd) DO(5, hrd) DO(6, hrd) DO(7, hrd) \
        const float ai = qsum4(aci.x + aci.y); \
        const float af = qsum4(acf.x + acf.y); \
        const float ag = qsum4(acg.x + acg.y); \
        const float ao = qsum4(aco.x + aco.y); \
        const float ig  = sigf(ai); \
        const float fg  = sigf(af); \
        const float gg2 = tanhf_fast(ag); \
        const float og  = sigf(ao); \
        c = fmaf(fg, c, ig * gg2); \
        const float hn = og * tanhf_fast(c); \
        if (lead) ((float*)hwr)[widx] = hn; \
        __syncthreads(); }

    const int Teven = T & ~1;
    for (int step = 0; step < Teven; step += 2) {
        STEP(hA, hB, step)        // even step: read A, write B
        STEP(hB, hA, step + 1)    // odd  step: read B, write A
    }
    if (T & 1) { STEP(hA, hB, T - 1) }
    const float* hf = (T & 1) ? (const float*)hB : (const float*)hA;
#undef STEP
#undef DO

    // Final linear: out = dot(W_lin, h_T) + b_lin (wave 0).
    if (t < 64) {
        const int e0 = t, e1 = t + 64;
        const int i0 = 8 * ((e0 & 31) >> 1) + 2 * (e0 >> 5) + (e0 & 1);
        const int i1 = 8 * ((e1 & 31) >> 1) + 2 * (e1 >> 5) + (e1 & 1);
        float v = Wlin[e0] * hf[i0] + Wlin[e1] * hf[i1];
        #pragma unroll
        for (int off = 32; off >= 1; off >>= 1) v += __shfl_down(v, off);
        if (t == 0) out[0] = v + blin[0];
    }
}

extern "C" void kernel_launch(void* const* d_in, const int* in_sizes, int n_in,
                              void* d_out, int out_size, void* d_ws, size_t ws_size,
                              hipStream_t stream) {
    const float* x    = (const float*)d_in[0];
    const float* Wih  = (const float*)d_in[1];
    const float* Whh  = (const float*)d_in[2];
    const float* bih  = (const float*)d_in[3];
    const float* bhh  = (const float*)d_in[4];
    const float* Wlin = (const float*)d_in[5];
    const float* blin = (const float*)d_in[6];
    const float* h0   = (const float*)d_in[7];
    const float* c0   = (const float*)d_in[8];
    float* out = (float*)d_out;
    const int T = in_sizes[0];

    lstm_seq_kernel<<<1, 512, 0, stream>>>(x, Wih, Whh, bih, bhh, Wlin, blin,
                                           h0, c0, out, T);
}